// Round 7
// baseline (250.240 us; speedup 1.0000x reference)
//
#include <hip/hip_runtime.h>
#include <hip/hip_bf16.h>
#include <stdint.h>

#define KDIM 4096
#define KSPLIT 2
#define KCHUNK (KDIM / KSPLIT)     // 2048 = 64 slices of 32
#define NSLICE (KCHUNK / 32)       // 64
#define DEPTH 4

typedef __attribute__((ext_vector_type(8))) short bf16x8;
typedef __attribute__((ext_vector_type(4))) float f32x4;

__device__ inline unsigned short f2bf_bits(float f) {
  union { __hip_bfloat16 h; unsigned short u; } cv;
  cv.h = __float2bfloat16(f);
  return cv.u;
}

// Fused quant+dequant for both tensors. One 8-lane subgroup = one 32-elem block.
// Palette selection via per-block thresholds (midpoint/6 * block_max);
// ties go to the LOWER palette value (argmin-first semantics).
__global__ void nvfp4_quant_dq2(const float* __restrict__ x, unsigned short* __restrict__ xq,
                                int nsub_x,
                                const float* __restrict__ w, unsigned short* __restrict__ wq,
                                int nsub_total) {
  int gid = blockIdx.x * blockDim.x + threadIdx.x;
  int sub = gid >> 3;
  if (sub >= nsub_total) return;
  const float* in;
  unsigned short* out;
  if (sub < nsub_x) { in = x; out = xq; }
  else { in = w; out = wq; sub -= nsub_x; }
  long base = (long)sub * 32 + (long)(gid & 7) * 4;
  const float4 v = *(const float4*)(in + base);
  float amax = fmaxf(fmaxf(fabsf(v.x), fabsf(v.y)), fmaxf(fabsf(v.z), fabsf(v.w)));
  amax = fmaxf(amax, __shfl_xor(amax, 1));
  amax = fmaxf(amax, __shfl_xor(amax, 2));
  amax = fmaxf(amax, __shfl_xor(amax, 4));
  const float bm = fmaxf(amax, 1e-12f);   // jnp.clip(max, 1e-12)
  const float scale = bm / 6.0f;

  const float T0 = bm * (0.25f / 6.0f);
  const float T1 = bm * (0.75f / 6.0f);
  const float T2 = bm * (1.25f / 6.0f);
  const float T3 = bm * (1.75f / 6.0f);
  const float T4 = bm * (2.5f  / 6.0f);
  const float T5 = bm * (3.5f  / 6.0f);
  const float T6 = bm * (5.0f  / 6.0f);

  float e[4] = {v.x, v.y, v.z, v.w};
  ushort4 o;
  unsigned short* op = (unsigned short*)&o;
#pragma unroll
  for (int i = 0; i < 4; i++) {
    float t = e[i];
    float a = fabsf(t);
    float p = 0.0f;
    p = (a > T0) ? 0.5f : p;
    p = (a > T1) ? 1.0f : p;
    p = (a > T2) ? 1.5f : p;
    p = (a > T3) ? 2.0f : p;
    p = (a > T4) ? 3.0f : p;
    p = (a > T5) ? 4.0f : p;
    p = (a > T6) ? 6.0f : p;
    op[i] = f2bf_bits(copysignf(p, t) * scale);
  }
  *(ushort4*)(out + base) = o;
}

#define MFMA(d, a, b) d = __builtin_amdgcn_mfma_f32_16x16x32_bf16(a, b, d, 0, 0, 0)

// Barrier-free register-pipelined GEMM: C[M,N] += A[M,K] * B[N,K]^T over
// K-chunk blockIdx.z. Block = 2x2 waves, 128x128 tile; wave tile 64x64
// (4x4 MFMA 16x16x32). Fragments load straight global->VGPR (no LDS, no
// __syncthreads, so the VMEM queue NEVER drains), software-pipelined
// DEPTH=4 slices ahead (32 loads in flight/wave). Grid (32,8,2) = 512
// blocks -> 2 blocks/CU, 2 waves/SIMD.
__global__ __launch_bounds__(256, 2) void gemm_pipe(
    const unsigned short* __restrict__ A,  // [M, K]
    const unsigned short* __restrict__ B,  // [N, K]
    float* __restrict__ C, int M, int N) {
  const int tid = threadIdx.x;
  const int wave = tid >> 6;
  const int lane = tid & 63;
  const int wm = wave >> 1;
  const int wn = wave & 1;
  const int quad = lane >> 4;     // 0..3
  const int r16 = lane & 15;      // 0..15

  const int bm0 = blockIdx.y * 128 + wm * 64;
  const int bn0 = blockIdx.x * 128 + wn * 64;
  const long kb = (long)blockIdx.z * KCHUNK;

  // Per-fragment-row base pointers (lane view): A[bm0+i*16+r16][kb+quad*8 + ...]
  const unsigned short* Ar[4];
  const unsigned short* Br[4];
#pragma unroll
  for (int i = 0; i < 4; i++) {
    Ar[i] = A + (long)(bm0 + i * 16 + r16) * KDIM + kb + quad * 8;
    Br[i] = B + (long)(bn0 + i * 16 + r16) * KDIM + kb + quad * 8;
  }

  bf16x8 ab[DEPTH][4], bb[DEPTH][4];

  // Prologue: load slices 0..3 into the 4 pipeline buffers.
#pragma unroll
  for (int t = 0; t < DEPTH; t++) {
#pragma unroll
    for (int i = 0; i < 4; i++) {
      ab[t][i] = *(const bf16x8*)(Ar[i] + t * 32);
      bb[t][i] = *(const bf16x8*)(Br[i] + t * 32);
    }
  }
  // Advance to slice DEPTH for the reload stream.
#pragma unroll
  for (int i = 0; i < 4; i++) { Ar[i] += DEPTH * 32; Br[i] += DEPTH * 32; }

  f32x4 acc[4][4] = {};

  // Steady state: 15 iterations x 4 stages. Stage t: compute slice from
  // buffer t (compiler emits fine-grained vmcnt for its 8 loads, issued
  // 4 stages = ~600 cyc earlier), then immediately reload buffer t.
  // No barrier anywhere -> loads stay in flight continuously.
#pragma unroll 1
  for (int it = 0; it < NSLICE / DEPTH - 1; ++it) {
#pragma unroll
    for (int t = 0; t < DEPTH; t++) {
#pragma unroll
      for (int i = 0; i < 4; i++)
#pragma unroll
        for (int j = 0; j < 4; j++)
          MFMA(acc[i][j], ab[t][i], bb[t][j]);
#pragma unroll
      for (int i = 0; i < 4; i++) {
        ab[t][i] = *(const bf16x8*)Ar[i];
        bb[t][i] = *(const bf16x8*)Br[i];
        Ar[i] += 32; Br[i] += 32;
      }
    }
  }
  // Tail: drain the last 4 buffers (slices 60..63).
#pragma unroll
  for (int t = 0; t < DEPTH; t++)
#pragma unroll
    for (int i = 0; i < 4; i++)
#pragma unroll
      for (int j = 0; j < 4; j++)
        MFMA(acc[i][j], ab[t][i], bb[t][j]);

  // Epilogue: C/D layout col = lane&15, row = quad*4 + reg.
  // Split-K=2 -> fp32 atomicAdd into zeroed output.
#pragma unroll
  for (int i = 0; i < 4; i++) {
#pragma unroll
    for (int j = 0; j < 4; j++) {
      const int row = bm0 + i * 16 + quad * 4;
      const int col = bn0 + j * 16 + r16;
#pragma unroll
      for (int r = 0; r < 4; r++)
        atomicAdd(&C[(long)(row + r) * N + col], acc[i][j][r]);
    }
  }
}

extern "C" void kernel_launch(void* const* d_in, const int* in_sizes, int n_in,
                              void* d_out, int out_size, void* d_ws, size_t ws_size,
                              hipStream_t stream) {
  const float* x = (const float*)d_in[0];   // [M, K] fp32
  const float* w = (const float*)d_in[1];   // [N, K] fp32
  float* out = (float*)d_out;               // [M, N] fp32

  const int MK = in_sizes[0];
  const int NK = in_sizes[1];
  const int M = MK / KDIM;
  const int N = NK / KDIM;

  unsigned short* xq = (unsigned short*)d_ws;        // [M, K] bf16
  unsigned short* wq = xq + (size_t)MK;              // [N, K] bf16

  // Zero the output for the atomic split-K epilogue (graph-capturable).
  hipMemsetAsync(out, 0, (size_t)out_size * sizeof(float), stream);

  const int nsub_x = MK / 32;
  const int nsub_total = nsub_x + NK / 32;
  nvfp4_quant_dq2<<<dim3((nsub_total * 8 + 255) / 256), dim3(256), 0, stream>>>(
      x, xq, nsub_x, w, wq, nsub_total);

  dim3 grid(N / 128, M / 128, KSPLIT);
  gemm_pipe<<<grid, dim3(256), 0, stream>>>(xq, wq, out, M, N);
}